// Round 8
// baseline (350.798 us; speedup 1.0000x reference)
//
#include <hip/hip_runtime.h>
#include <hip/hip_bf16.h>
#include <math.h>

#define NNODES 50000
#define NEDGES 500000
#define ETOT   (NEDGES + NNODES)
#define DIN    128
#define CH     256
#define SLOPE  0.2f

#define SCAN_TILE 1024
#define NSCAN ((NNODES + SCAN_TILE - 1) / SCAN_TILE)   // 49

typedef __attribute__((ext_vector_type(8))) short short8;
typedef __attribute__((ext_vector_type(4))) float f32x4;

static __device__ __forceinline__ float wave_reduce_max(float v) {
#pragma unroll
  for (int off = 32; off > 0; off >>= 1) v = fmaxf(v, __shfl_xor(v, off));
  return v;
}
static __device__ __forceinline__ float wave_reduce_sum(float v) {
#pragma unroll
  for (int off = 32; off > 0; off >>= 1) v += __shfl_xor(v, off);
  return v;
}

static __device__ __forceinline__ unsigned short f2bf(float f) {
  unsigned int u = __float_as_uint(f);
  unsigned int r = (u + 0x7fffu + ((u >> 16) & 1u)) >> 16;
  return (unsigned short)r;
}
static __device__ __forceinline__ float bf2f(unsigned short u) {
  return __uint_as_float(((unsigned int)u) << 16);
}

// ---------------- CSR build (dst-sorted) ----------------
__global__ void degree_kernel(const int* __restrict__ ei, int* __restrict__ deg) {
  int e = blockIdx.x * blockDim.x + threadIdx.x;
  if (e >= ETOT) return;
  int dst = (e < NEDGES) ? ei[NEDGES + e] : (e - NEDGES);
  atomicAdd(&deg[dst], 1);
}

__global__ __launch_bounds__(256) void scan_blocksums(const int* __restrict__ deg,
                                                      int* __restrict__ bsums) {
  __shared__ int sdata[4];
  int b = blockIdx.x;
  int tid = threadIdx.x;
  int idx = b * SCAN_TILE + tid * 4;
  int s = 0;
  if (idx + 3 < NNODES) {
    int4 v = *(const int4*)(deg + idx);
    s = v.x + v.y + v.z + v.w;
  } else {
#pragma unroll
    for (int j = 0; j < 4; j++) if (idx + j < NNODES) s += deg[idx + j];
  }
#pragma unroll
  for (int off = 32; off > 0; off >>= 1) s += __shfl_xor(s, off);
  if ((tid & 63) == 0) sdata[tid >> 6] = s;
  __syncthreads();
  if (tid == 0) bsums[b] = sdata[0] + sdata[1] + sdata[2] + sdata[3];
}

__global__ __launch_bounds__(64) void scan_bsums(const int* __restrict__ bsums,
                                                 int* __restrict__ boffs,
                                                 int* __restrict__ rowptr) {
  int tid = threadIdx.x;
  int v = (tid < NSCAN) ? bsums[tid] : 0;
  int x = v;
#pragma unroll
  for (int off = 1; off < 64; off <<= 1) {
    int t = __shfl_up(x, off);
    if (tid >= off) x += t;
  }
  if (tid < NSCAN) boffs[tid] = x - v;
  if (tid == 63) rowptr[NNODES] = x;
}

__global__ __launch_bounds__(256) void scan_final(const int* __restrict__ deg,
                                                  const int* __restrict__ boffs,
                                                  int* __restrict__ rowptr,
                                                  int* __restrict__ cursor) {
  __shared__ int wsums[4];
  int b = blockIdx.x;
  int tid = threadIdx.x;
  int lane = tid & 63;
  int base = b * SCAN_TILE + tid * 4;
  int d[4];
  int s = 0;
#pragma unroll
  for (int j = 0; j < 4; j++) {
    d[j] = (base + j < NNODES) ? deg[base + j] : 0;
    s += d[j];
  }
  int x = s;
#pragma unroll
  for (int off = 1; off < 64; off <<= 1) {
    int t = __shfl_up(x, off);
    if (lane >= off) x += t;
  }
  if (lane == 63) wsums[tid >> 6] = x;
  __syncthreads();
  int woff = 0;
  int w = tid >> 6;
  for (int i = 0; i < w; i++) woff += wsums[i];
  int excl = boffs[b] + woff + (x - s);
#pragma unroll
  for (int j = 0; j < 4; j++) {
    if (base + j < NNODES) { rowptr[base + j] = excl; cursor[base + j] = excl; }
    excl += d[j];
  }
}

__global__ void scatter_kernel(const int* __restrict__ ei, int* __restrict__ cursor,
                               int* __restrict__ csr_src) {
  int e = blockIdx.x * blockDim.x + threadIdx.x;
  if (e >= ETOT) return;
  int src, dst;
  if (e < NEDGES) { src = ei[e]; dst = ei[NEDGES + e]; }
  else            { src = e - NEDGES; dst = src; }
  int slot = atomicAdd(&cursor[dst], 1);
  csr_src[slot] = src;
}

// ---------------- cast helper (weights only now) ----------------
__global__ void cast_f32_bf16(const float* __restrict__ in,
                              unsigned short* __restrict__ outp, int n4) {
  int i = blockIdx.x * blockDim.x + threadIdx.x;
  if (i >= n4) return;
  float4 v = *(const float4*)(in + (size_t)i * 4);
  ushort4 o;
  o.x = f2bf(v.x); o.y = f2bf(v.y); o.z = f2bf(v.z); o.w = f2bf(v.w);
  *(ushort4*)(outp + (size_t)i * 4) = o;
}

// ---------------- bf16 MFMA GEMM + fused attention-score epilogue ----------------
// Hb[m][c] = bf16(sum_k X[m][k]*W[c][k]);  eS[m] += sum_c h*a_src, eD likewise.
// X source: Xf (fp32, converted in staging) if non-null, else Xb (bf16).
#define TM 128
#define TN 128
#define TK 64
#define LDA (TK + 8)

__global__ __launch_bounds__(256) void gemm_bf16(
    const float* __restrict__ Xf, const unsigned short* __restrict__ Xb, int ldx,
    const unsigned short* __restrict__ W, int K,
    unsigned short* __restrict__ Hout, int M,
    const float* __restrict__ a_src, const float* __restrict__ a_dst,
    float* __restrict__ eS, float* __restrict__ eD) {
  __shared__ short As[TM * LDA];
  __shared__ short Bs[TN * LDA];
  int bm = blockIdx.y * TM;
  int bn = blockIdx.x * TN;
  int tid = threadIdx.x;
  int wid = tid >> 6;
  int lane = tid & 63;
  int wm = (wid & 1) * 64;
  int wn = (wid >> 1) * 64;
  int lrow = lane & 15;
  int lk8 = (lane >> 4) * 8;

  int srow = tid >> 3;
  int skoff = (tid & 7) * 8;

  f32x4 acc[4][4] = {};

  for (int k0 = 0; k0 < K; k0 += TK) {
#pragma unroll
    for (int i = 0; i < 4; i++) {
      int r = srow + 32 * i;
      int gm = bm + r;
      short8 v = {};
      if (gm < M) {
        if (Xf) {
          const float* p = Xf + (size_t)gm * ldx + k0 + skoff;
          float4 f0 = *(const float4*)(p);
          float4 f1 = *(const float4*)(p + 4);
          v[0] = (short)f2bf(f0.x); v[1] = (short)f2bf(f0.y);
          v[2] = (short)f2bf(f0.z); v[3] = (short)f2bf(f0.w);
          v[4] = (short)f2bf(f1.x); v[5] = (short)f2bf(f1.y);
          v[6] = (short)f2bf(f1.z); v[7] = (short)f2bf(f1.w);
        } else {
          v = *(const short8*)(Xb + (size_t)gm * ldx + k0 + skoff);
        }
      }
      *(short8*)(&As[r * LDA + skoff]) = v;
      short8 w = *(const short8*)(W + (size_t)(bn + r) * K + k0 + skoff);
      *(short8*)(&Bs[r * LDA + skoff]) = w;
    }
    __syncthreads();
#pragma unroll
    for (int kk = 0; kk < TK; kk += 32) {
      short8 a[4], b[4];
#pragma unroll
      for (int mi = 0; mi < 4; mi++)
        a[mi] = *(const short8*)(&As[(wm + mi * 16 + lrow) * LDA + kk + lk8]);
#pragma unroll
      for (int ni = 0; ni < 4; ni++)
        b[ni] = *(const short8*)(&Bs[(wn + ni * 16 + lrow) * LDA + kk + lk8]);
#pragma unroll
      for (int mi = 0; mi < 4; mi++)
#pragma unroll
        for (int ni = 0; ni < 4; ni++)
          acc[mi][ni] = __builtin_amdgcn_mfma_f32_16x16x32_bf16(a[mi], b[ni], acc[mi][ni], 0, 0, 0);
    }
    __syncthreads();
  }

  int crow = (lane >> 4) * 4;
  int ccol = lane & 15;

  // ---- C-store (bf16) ----
#pragma unroll
  for (int mi = 0; mi < 4; mi++) {
#pragma unroll
    for (int ni = 0; ni < 4; ni++) {
#pragma unroll
      for (int r = 0; r < 4; r++) {
        int gm = bm + wm + mi * 16 + crow + r;
        if (gm < M)
          Hout[(size_t)gm * CH + bn + wn + ni * 16 + ccol] = f2bf(acc[mi][ni][r]);
      }
    }
  }

  // ---- fused score epilogue: eS/eD partial dots over this block's 128 cols ----
  float asv[4], adv[4];
#pragma unroll
  for (int ni = 0; ni < 4; ni++) {
    int c = bn + wn + ni * 16 + ccol;
    asv[ni] = a_src[c];
    adv[ni] = a_dst[c];
  }
#pragma unroll
  for (int mi = 0; mi < 4; mi++) {
#pragma unroll
    for (int r = 0; r < 4; r++) {
      float s = 0.f, d = 0.f;
#pragma unroll
      for (int ni = 0; ni < 4; ni++) {
        float h = acc[mi][ni][r];
        s += h * asv[ni];
        d += h * adv[ni];
      }
      // reduce over the 16-lane column group
#pragma unroll
      for (int off = 1; off < 16; off <<= 1) {
        s += __shfl_xor(s, off);
        d += __shfl_xor(d, off);
      }
      int gm = bm + wm + mi * 16 + crow + r;
      if (ccol == 0 && gm < M) {
        atomicAdd(&eS[gm], s);
        atomicAdd(&eD[gm], d);
      }
    }
  }
}

// ---------------- per-node softmax + aggregate (+bias, +ReLU) ----------------
// Wave per node (4/block). Fast path deg<=64: lane i owns edge i, all softmax
// state in registers; weighted pass keeps 8 independent row gathers in flight.
__global__ __launch_bounds__(256) void aggregate_kernel(
    const unsigned short* __restrict__ Hmb, const float* __restrict__ eS,
    const float* __restrict__ eD, const int* __restrict__ rowptr,
    const int* __restrict__ csr_src, const float* __restrict__ bias,
    float* __restrict__ out, int outOffset, unsigned short* __restrict__ xout) {
  int n = blockIdx.x * 4 + (threadIdx.x >> 6);
  if (n >= NNODES) return;
  int lane = threadIdx.x & 63;
  int beg = rowptr[n], end = rowptr[n + 1];
  int deg = end - beg;
  float ed = eD[n];

  float4 acc = make_float4(0.f, 0.f, 0.f, 0.f);

  if (deg <= 64) {
    int src = 0;
    float e = -1e30f;
    if (lane < deg) {
      src = csr_src[beg + lane];              // coalesced
      float t = eS[src] + ed;                 // lane-parallel gather
      e = (t >= 0.f) ? t : SLOPE * t;
    }
    float m = wave_reduce_max(e);
    float p = (lane < deg) ? __expf(e - m) : 0.f;
    float inv = 1.f / (wave_reduce_sum(p) + 1e-16f);

    for (int j0 = 0; j0 < deg; j0 += 8) {
      ushort4 hv[8];
      float al[8];
#pragma unroll
      for (int t = 0; t < 8; t++) {
        int j = j0 + t;
        int jj = (j < deg) ? j : deg - 1;     // tail dups last edge (L1-hot)
        int sj = __shfl(src, jj);
        float aj = __shfl(p, jj) * inv;
        al[t] = (j < deg) ? aj : 0.f;
        hv[t] = *(const ushort4*)(Hmb + (size_t)sj * CH + lane * 4);
      }
#pragma unroll
      for (int t = 0; t < 8; t++) {
        acc.x += al[t] * bf2f(hv[t].x);
        acc.y += al[t] * bf2f(hv[t].y);
        acc.z += al[t] * bf2f(hv[t].z);
        acc.w += al[t] * bf2f(hv[t].w);
      }
    }
  } else {
    float m = -1e30f;
    for (int i = lane; i < deg; i += 64) {
      float e = eS[csr_src[beg + i]] + ed;
      e = (e >= 0.f) ? e : SLOPE * e;
      m = fmaxf(m, e);
    }
    m = wave_reduce_max(m);
    float ds = 0.f;
    for (int i = lane; i < deg; i += 64) {
      float e = eS[csr_src[beg + i]] + ed;
      e = (e >= 0.f) ? e : SLOPE * e;
      ds += __expf(e - m);
    }
    ds = wave_reduce_sum(ds) + 1e-16f;
    float inv = 1.f / ds;
    for (int k = beg; k < end; k++) {
      int s = csr_src[k];
      float e = eS[s] + ed;
      e = (e >= 0.f) ? e : SLOPE * e;
      float alpha = __expf(e - m) * inv;
      ushort4 hu = *(const ushort4*)(Hmb + (size_t)s * CH + lane * 4);
      acc.x += alpha * bf2f(hu.x); acc.y += alpha * bf2f(hu.y);
      acc.z += alpha * bf2f(hu.z); acc.w += alpha * bf2f(hu.w);
    }
  }

  float4 b = *(const float4*)(bias + lane * 4);
  float4 o;
  o.x = fmaxf(acc.x + b.x, 0.f);
  o.y = fmaxf(acc.y + b.y, 0.f);
  o.z = fmaxf(acc.z + b.z, 0.f);
  o.w = fmaxf(acc.w + b.w, 0.f);
  *(float4*)(out + (size_t)n * 512 + outOffset + lane * 4) = o;
  if (xout) {
    ushort4 ob;
    ob.x = f2bf(o.x); ob.y = f2bf(o.y); ob.z = f2bf(o.z); ob.w = f2bf(o.w);
    *(ushort4*)(xout + (size_t)n * CH + lane * 4) = ob;
  }
}

extern "C" void kernel_launch(void* const* d_in, const int* in_sizes, int n_in,
                              void* d_out, int out_size, void* d_ws, size_t ws_size,
                              hipStream_t stream) {
  const float* x   = (const float*)d_in[0];
  const int*   ei  = (const int*)d_in[1];
  const float* W1  = (const float*)d_in[2];
  const float* a1s = (const float*)d_in[3];
  const float* a1d = (const float*)d_in[4];
  const float* b1  = (const float*)d_in[5];
  const float* W2  = (const float*)d_in[6];
  const float* a2s = (const float*)d_in[7];
  const float* a2d = (const float*)d_in[8];
  const float* b2  = (const float*)d_in[9];
  float* out = (float*)d_out;

  char* ws = (char*)d_ws;
  size_t off = 0;
  auto alloc = [&](size_t bytes) -> void* {
    void* p = ws + off;
    off = (off + bytes + 255) & ~(size_t)255;
    return p;
  };
  unsigned short* Hmb    = (unsigned short*)alloc(sizeof(short) * (size_t)NNODES * CH);
  unsigned short* Xb     = (unsigned short*)alloc(sizeof(short) * (size_t)NNODES * CH);
  unsigned short* Wb     = (unsigned short*)alloc(sizeof(short) * CH * CH);
  float*          eS     = (float*)alloc(sizeof(float) * NNODES);
  float*          eD     = (float*)alloc(sizeof(float) * NNODES);
  int*            rowptr = (int*)alloc(sizeof(int) * (NNODES + 1));
  int*            cursor = (int*)alloc(sizeof(int) * NNODES);
  int*            csrsrc = (int*)alloc(sizeof(int) * ETOT);
  int*            deg    = (int*)alloc(sizeof(int) * NNODES);
  int*            bsums  = (int*)alloc(sizeof(int) * NSCAN);
  int*            boffs  = (int*)alloc(sizeof(int) * NSCAN);

  // CSR build (edge list identical for both layers)
  hipMemsetAsync(deg, 0, sizeof(int) * NNODES, stream);
  degree_kernel<<<(ETOT + 255) / 256, 256, 0, stream>>>(ei, deg);
  scan_blocksums<<<NSCAN, 256, 0, stream>>>(deg, bsums);
  scan_bsums<<<1, 64, 0, stream>>>(bsums, boffs, rowptr);
  scan_final<<<NSCAN, 256, 0, stream>>>(deg, boffs, rowptr, cursor);
  scatter_kernel<<<(ETOT + 255) / 256, 256, 0, stream>>>(ei, cursor, csrsrc);

  dim3 gemm_grid(2, (NNODES + TM - 1) / TM);
  int nblk4 = (NNODES + 3) / 4;

  // ---- layer 1 (x fp32 converted in GEMM staging; score fused in epilogue) ----
  {
    int w4 = CH * DIN / 4;
    cast_f32_bf16<<<(w4 + 255) / 256, 256, 0, stream>>>(W1, Wb, w4);
  }
  hipMemsetAsync(eS, 0, sizeof(float) * NNODES, stream);
  hipMemsetAsync(eD, 0, sizeof(float) * NNODES, stream);
  gemm_bf16<<<gemm_grid, 256, 0, stream>>>(x, (const unsigned short*)nullptr, DIN,
                                           Wb, DIN, Hmb, NNODES, a1s, a1d, eS, eD);
  aggregate_kernel<<<nblk4, 256, 0, stream>>>(Hmb, eS, eD, rowptr, csrsrc, b1, out, 0, Xb);

  // ---- layer 2 ----
  {
    int w4 = CH * CH / 4;
    cast_f32_bf16<<<(w4 + 255) / 256, 256, 0, stream>>>(W2, Wb, w4);
  }
  hipMemsetAsync(eS, 0, sizeof(float) * NNODES, stream);
  hipMemsetAsync(eD, 0, sizeof(float) * NNODES, stream);
  gemm_bf16<<<gemm_grid, 256, 0, stream>>>((const float*)nullptr, Xb, CH,
                                           Wb, CH, Hmb, NNODES, a2s, a2d, eS, eD);
  aggregate_kernel<<<nblk4, 256, 0, stream>>>(Hmb, eS, eD, rowptr, csrsrc, b2, out, 256, (unsigned short*)nullptr);
}

// Round 9
// 335.498 us; speedup vs baseline: 1.0456x; 1.0456x over previous
//
#include <hip/hip_runtime.h>
#include <hip/hip_bf16.h>
#include <math.h>

#define NNODES 50000
#define NEDGES 500000
#define ETOT   (NEDGES + NNODES)
#define DIN    128
#define CH     256
#define SLOPE  0.2f

#define SCAN_TILE 1024
#define NSCAN ((NNODES + SCAN_TILE - 1) / SCAN_TILE)   // 49

typedef __attribute__((ext_vector_type(8))) short short8;
typedef __attribute__((ext_vector_type(4))) float f32x4;

static __device__ __forceinline__ float wave_reduce_max(float v) {
#pragma unroll
  for (int off = 32; off > 0; off >>= 1) v = fmaxf(v, __shfl_xor(v, off));
  return v;
}
static __device__ __forceinline__ float wave_reduce_sum(float v) {
#pragma unroll
  for (int off = 32; off > 0; off >>= 1) v += __shfl_xor(v, off);
  return v;
}

static __device__ __forceinline__ unsigned short f2bf(float f) {
  unsigned int u = __float_as_uint(f);
  unsigned int r = (u + 0x7fffu + ((u >> 16) & 1u)) >> 16;
  return (unsigned short)r;
}
static __device__ __forceinline__ float bf2f(unsigned short u) {
  return __uint_as_float(((unsigned int)u) << 16);
}

// ---------------- init: zero deg + both layers' score buffers ----------------
__global__ __launch_bounds__(256) void init_kernel(int* __restrict__ deg,
                                                   float* __restrict__ eS1, float* __restrict__ eD1,
                                                   float* __restrict__ eS2, float* __restrict__ eD2) {
  int i = blockIdx.x * 256 + threadIdx.x;
  if (i < NNODES) {
    deg[i] = 0;
    eS1[i] = 0.f; eD1[i] = 0.f;
    eS2[i] = 0.f; eD2[i] = 0.f;
  }
}

// ---------------- CSR build (dst-sorted) ----------------
__global__ void degree_kernel(const int* __restrict__ ei, int* __restrict__ deg) {
  int e = blockIdx.x * blockDim.x + threadIdx.x;
  if (e >= ETOT) return;
  int dst = (e < NEDGES) ? ei[NEDGES + e] : (e - NEDGES);
  atomicAdd(&deg[dst], 1);
}

__global__ __launch_bounds__(256) void scan_blocksums(const int* __restrict__ deg,
                                                      int* __restrict__ bsums) {
  __shared__ int sdata[4];
  int b = blockIdx.x;
  int tid = threadIdx.x;
  int idx = b * SCAN_TILE + tid * 4;
  int s = 0;
  if (idx + 3 < NNODES) {
    int4 v = *(const int4*)(deg + idx);
    s = v.x + v.y + v.z + v.w;
  } else {
#pragma unroll
    for (int j = 0; j < 4; j++) if (idx + j < NNODES) s += deg[idx + j];
  }
#pragma unroll
  for (int off = 32; off > 0; off >>= 1) s += __shfl_xor(s, off);
  if ((tid & 63) == 0) sdata[tid >> 6] = s;
  __syncthreads();
  if (tid == 0) bsums[b] = sdata[0] + sdata[1] + sdata[2] + sdata[3];
}

__global__ __launch_bounds__(64) void scan_bsums(const int* __restrict__ bsums,
                                                 int* __restrict__ boffs,
                                                 int* __restrict__ rowptr) {
  int tid = threadIdx.x;
  int v = (tid < NSCAN) ? bsums[tid] : 0;
  int x = v;
#pragma unroll
  for (int off = 1; off < 64; off <<= 1) {
    int t = __shfl_up(x, off);
    if (tid >= off) x += t;
  }
  if (tid < NSCAN) boffs[tid] = x - v;
  if (tid == 63) rowptr[NNODES] = x;
}

__global__ __launch_bounds__(256) void scan_final(const int* __restrict__ deg,
                                                  const int* __restrict__ boffs,
                                                  int* __restrict__ rowptr,
                                                  int* __restrict__ cursor) {
  __shared__ int wsums[4];
  int b = blockIdx.x;
  int tid = threadIdx.x;
  int lane = tid & 63;
  int base = b * SCAN_TILE + tid * 4;
  int d[4];
  int s = 0;
#pragma unroll
  for (int j = 0; j < 4; j++) {
    d[j] = (base + j < NNODES) ? deg[base + j] : 0;
    s += d[j];
  }
  int x = s;
#pragma unroll
  for (int off = 1; off < 64; off <<= 1) {
    int t = __shfl_up(x, off);
    if (lane >= off) x += t;
  }
  if (lane == 63) wsums[tid >> 6] = x;
  __syncthreads();
  int woff = 0;
  int w = tid >> 6;
  for (int i = 0; i < w; i++) woff += wsums[i];
  int excl = boffs[b] + woff + (x - s);
#pragma unroll
  for (int j = 0; j < 4; j++) {
    if (base + j < NNODES) { rowptr[base + j] = excl; cursor[base + j] = excl; }
    excl += d[j];
  }
}

__global__ void scatter_kernel(const int* __restrict__ ei, int* __restrict__ cursor,
                               int* __restrict__ csr_src) {
  int e = blockIdx.x * blockDim.x + threadIdx.x;
  if (e >= ETOT) return;
  int src, dst;
  if (e < NEDGES) { src = ei[e]; dst = ei[NEDGES + e]; }
  else            { src = e - NEDGES; dst = src; }
  int slot = atomicAdd(&cursor[dst], 1);
  csr_src[slot] = src;
}

// ---------------- fused weight cast: W1 and W2 in one dispatch ----------------
#define W1N4 (CH * DIN / 4)   // 8192
#define W2N4 (CH * CH / 4)    // 16384
__global__ __launch_bounds__(256) void cast_weights(const float* __restrict__ W1,
                                                    const float* __restrict__ W2,
                                                    unsigned short* __restrict__ Wb1,
                                                    unsigned short* __restrict__ Wb2) {
  int i = blockIdx.x * 256 + threadIdx.x;
  const float* src;
  unsigned short* dst;
  int j;
  if (i < W1N4) { src = W1; dst = Wb1; j = i; }
  else if (i < W1N4 + W2N4) { src = W2; dst = Wb2; j = i - W1N4; }
  else return;
  float4 v = *(const float4*)(src + (size_t)j * 4);
  ushort4 o;
  o.x = f2bf(v.x); o.y = f2bf(v.y); o.z = f2bf(v.z); o.w = f2bf(v.w);
  *(ushort4*)(dst + (size_t)j * 4) = o;
}

// ---------------- bf16 MFMA GEMM + fused attention-score epilogue ----------------
// Hb[m][c] = bf16(sum_k X[m][k]*W[c][k]);  eS[m] += sum_c h*a_src, eD likewise.
// C-store goes through a padded LDS tile -> coalesced short8 global stores.
#define TM 128
#define TN 128
#define TK 64
#define LDA (TK + 8)
#define LDC (TN + 8)   // 136 shorts: row stride 68 words -> banks rotate by 4

__global__ __launch_bounds__(256) void gemm_bf16(
    const float* __restrict__ Xf, const unsigned short* __restrict__ Xb, int ldx,
    const unsigned short* __restrict__ W, int K,
    unsigned short* __restrict__ Hout, int M,
    const float* __restrict__ a_src, const float* __restrict__ a_dst,
    float* __restrict__ eS, float* __restrict__ eD) {
  __shared__ short smem[TM * LDA * 2];   // As | Bs ; reused as Cs (TM*LDC <= 2*TM*LDA)
  short* As = smem;
  short* Bs = smem + TM * LDA;
  short* Cs = smem;
  int bm = blockIdx.y * TM;
  int bn = blockIdx.x * TN;
  int tid = threadIdx.x;
  int wid = tid >> 6;
  int lane = tid & 63;
  int wm = (wid & 1) * 64;
  int wn = (wid >> 1) * 64;
  int lrow = lane & 15;
  int lk8 = (lane >> 4) * 8;

  int srow = tid >> 3;
  int skoff = (tid & 7) * 8;

  f32x4 acc[4][4] = {};

  for (int k0 = 0; k0 < K; k0 += TK) {
#pragma unroll
    for (int i = 0; i < 4; i++) {
      int r = srow + 32 * i;
      int gm = bm + r;
      short8 v = {};
      if (gm < M) {
        if (Xf) {
          const float* p = Xf + (size_t)gm * ldx + k0 + skoff;
          float4 f0 = *(const float4*)(p);
          float4 f1 = *(const float4*)(p + 4);
          v[0] = (short)f2bf(f0.x); v[1] = (short)f2bf(f0.y);
          v[2] = (short)f2bf(f0.z); v[3] = (short)f2bf(f0.w);
          v[4] = (short)f2bf(f1.x); v[5] = (short)f2bf(f1.y);
          v[6] = (short)f2bf(f1.z); v[7] = (short)f2bf(f1.w);
        } else {
          v = *(const short8*)(Xb + (size_t)gm * ldx + k0 + skoff);
        }
      }
      *(short8*)(&As[r * LDA + skoff]) = v;
      short8 w = *(const short8*)(W + (size_t)(bn + r) * K + k0 + skoff);
      *(short8*)(&Bs[r * LDA + skoff]) = w;
    }
    __syncthreads();
#pragma unroll
    for (int kk = 0; kk < TK; kk += 32) {
      short8 a[4], b[4];
#pragma unroll
      for (int mi = 0; mi < 4; mi++)
        a[mi] = *(const short8*)(&As[(wm + mi * 16 + lrow) * LDA + kk + lk8]);
#pragma unroll
      for (int ni = 0; ni < 4; ni++)
        b[ni] = *(const short8*)(&Bs[(wn + ni * 16 + lrow) * LDA + kk + lk8]);
#pragma unroll
      for (int mi = 0; mi < 4; mi++)
#pragma unroll
        for (int ni = 0; ni < 4; ni++)
          acc[mi][ni] = __builtin_amdgcn_mfma_f32_16x16x32_bf16(a[mi], b[ni], acc[mi][ni], 0, 0, 0);
    }
    __syncthreads();
  }

  int crow = (lane >> 4) * 4;
  int ccol = lane & 15;

  // ---- fused score epilogue (registers only; before LDS reuse) ----
  float asv[4], adv[4];
#pragma unroll
  for (int ni = 0; ni < 4; ni++) {
    int c = bn + wn + ni * 16 + ccol;
    asv[ni] = a_src[c];
    adv[ni] = a_dst[c];
  }
#pragma unroll
  for (int mi = 0; mi < 4; mi++) {
#pragma unroll
    for (int r = 0; r < 4; r++) {
      float s = 0.f, d = 0.f;
#pragma unroll
      for (int ni = 0; ni < 4; ni++) {
        float h = acc[mi][ni][r];
        s += h * asv[ni];
        d += h * adv[ni];
      }
#pragma unroll
      for (int off = 1; off < 16; off <<= 1) {
        s += __shfl_xor(s, off);
        d += __shfl_xor(d, off);
      }
      int gm = bm + wm + mi * 16 + crow + r;
      if (ccol == 0 && gm < M) {
        atomicAdd(&eS[gm], s);
        atomicAdd(&eD[gm], d);
      }
    }
  }

  // ---- C-store via LDS: scatter bf16 into padded tile, read out coalesced ----
#pragma unroll
  for (int mi = 0; mi < 4; mi++) {
#pragma unroll
    for (int ni = 0; ni < 4; ni++) {
#pragma unroll
      for (int r = 0; r < 4; r++) {
        int row = wm + mi * 16 + crow + r;
        int col = wn + ni * 16 + ccol;
        Cs[row * LDC + col] = (short)f2bf(acc[mi][ni][r]);
      }
    }
  }
  __syncthreads();
  int orow = tid >> 4;          // 0..15
  int ocol = (tid & 15) * 8;    // 0..120
#pragma unroll
  for (int pp = 0; pp < 8; pp++) {
    int row = pp * 16 + orow;
    int gm = bm + row;
    if (gm < M) {
      short8 v = *(const short8*)(&Cs[row * LDC + ocol]);
      *(short8*)(&Hout[(size_t)gm * CH + bn + ocol]) = v;
    }
  }
}

// ---------------- per-node softmax + aggregate (+bias, +ReLU) ----------------
// Wave per node (4/block). Fast path deg<=64: lane i owns edge i, all softmax
// state in registers; weighted pass keeps 8 independent row gathers in flight.
__global__ __launch_bounds__(256) void aggregate_kernel(
    const unsigned short* __restrict__ Hmb, const float* __restrict__ eS,
    const float* __restrict__ eD, const int* __restrict__ rowptr,
    const int* __restrict__ csr_src, const float* __restrict__ bias,
    float* __restrict__ out, int outOffset, unsigned short* __restrict__ xout) {
  int n = blockIdx.x * 4 + (threadIdx.x >> 6);
  if (n >= NNODES) return;
  int lane = threadIdx.x & 63;
  int beg = rowptr[n], end = rowptr[n + 1];
  int deg = end - beg;
  float ed = eD[n];

  float4 acc = make_float4(0.f, 0.f, 0.f, 0.f);

  if (deg <= 64) {
    int src = 0;
    float e = -1e30f;
    if (lane < deg) {
      src = csr_src[beg + lane];              // coalesced
      float t = eS[src] + ed;                 // lane-parallel gather
      e = (t >= 0.f) ? t : SLOPE * t;
    }
    float m = wave_reduce_max(e);
    float p = (lane < deg) ? __expf(e - m) : 0.f;
    float inv = 1.f / (wave_reduce_sum(p) + 1e-16f);

    for (int j0 = 0; j0 < deg; j0 += 8) {
      ushort4 hv[8];
      float al[8];
#pragma unroll
      for (int t = 0; t < 8; t++) {
        int j = j0 + t;
        int jj = (j < deg) ? j : deg - 1;     // tail dups last edge (L1-hot)
        int sj = __shfl(src, jj);
        float aj = __shfl(p, jj) * inv;
        al[t] = (j < deg) ? aj : 0.f;
        hv[t] = *(const ushort4*)(Hmb + (size_t)sj * CH + lane * 4);
      }
#pragma unroll
      for (int t = 0; t < 8; t++) {
        acc.x += al[t] * bf2f(hv[t].x);
        acc.y += al[t] * bf2f(hv[t].y);
        acc.z += al[t] * bf2f(hv[t].z);
        acc.w += al[t] * bf2f(hv[t].w);
      }
    }
  } else {
    float m = -1e30f;
    for (int i = lane; i < deg; i += 64) {
      float e = eS[csr_src[beg + i]] + ed;
      e = (e >= 0.f) ? e : SLOPE * e;
      m = fmaxf(m, e);
    }
    m = wave_reduce_max(m);
    float ds = 0.f;
    for (int i = lane; i < deg; i += 64) {
      float e = eS[csr_src[beg + i]] + ed;
      e = (e >= 0.f) ? e : SLOPE * e;
      ds += __expf(e - m);
    }
    ds = wave_reduce_sum(ds) + 1e-16f;
    float inv = 1.f / ds;
    for (int k = beg; k < end; k++) {
      int s = csr_src[k];
      float e = eS[s] + ed;
      e = (e >= 0.f) ? e : SLOPE * e;
      float alpha = __expf(e - m) * inv;
      ushort4 hu = *(const ushort4*)(Hmb + (size_t)s * CH + lane * 4);
      acc.x += alpha * bf2f(hu.x); acc.y += alpha * bf2f(hu.y);
      acc.z += alpha * bf2f(hu.z); acc.w += alpha * bf2f(hu.w);
    }
  }

  float4 b = *(const float4*)(bias + lane * 4);
  float4 o;
  o.x = fmaxf(acc.x + b.x, 0.f);
  o.y = fmaxf(acc.y + b.y, 0.f);
  o.z = fmaxf(acc.z + b.z, 0.f);
  o.w = fmaxf(acc.w + b.w, 0.f);
  *(float4*)(out + (size_t)n * 512 + outOffset + lane * 4) = o;
  if (xout) {
    ushort4 ob;
    ob.x = f2bf(o.x); ob.y = f2bf(o.y); ob.z = f2bf(o.z); ob.w = f2bf(o.w);
    *(ushort4*)(xout + (size_t)n * CH + lane * 4) = ob;
  }
}

extern "C" void kernel_launch(void* const* d_in, const int* in_sizes, int n_in,
                              void* d_out, int out_size, void* d_ws, size_t ws_size,
                              hipStream_t stream) {
  const float* x   = (const float*)d_in[0];
  const int*   ei  = (const int*)d_in[1];
  const float* W1  = (const float*)d_in[2];
  const float* a1s = (const float*)d_in[3];
  const float* a1d = (const float*)d_in[4];
  const float* b1  = (const float*)d_in[5];
  const float* W2  = (const float*)d_in[6];
  const float* a2s = (const float*)d_in[7];
  const float* a2d = (const float*)d_in[8];
  const float* b2  = (const float*)d_in[9];
  float* out = (float*)d_out;

  char* ws = (char*)d_ws;
  size_t off = 0;
  auto alloc = [&](size_t bytes) -> void* {
    void* p = ws + off;
    off = (off + bytes + 255) & ~(size_t)255;
    return p;
  };
  unsigned short* Hmb    = (unsigned short*)alloc(sizeof(short) * (size_t)NNODES * CH);
  unsigned short* Xb     = (unsigned short*)alloc(sizeof(short) * (size_t)NNODES * CH);
  unsigned short* Wb1    = (unsigned short*)alloc(sizeof(short) * CH * DIN);
  unsigned short* Wb2    = (unsigned short*)alloc(sizeof(short) * CH * CH);
  float*          eS1    = (float*)alloc(sizeof(float) * NNODES);
  float*          eD1    = (float*)alloc(sizeof(float) * NNODES);
  float*          eS2    = (float*)alloc(sizeof(float) * NNODES);
  float*          eD2    = (float*)alloc(sizeof(float) * NNODES);
  int*            rowptr = (int*)alloc(sizeof(int) * (NNODES + 1));
  int*            cursor = (int*)alloc(sizeof(int) * NNODES);
  int*            csrsrc = (int*)alloc(sizeof(int) * ETOT);
  int*            deg    = (int*)alloc(sizeof(int) * NNODES);
  int*            bsums  = (int*)alloc(sizeof(int) * NSCAN);
  int*            boffs  = (int*)alloc(sizeof(int) * NSCAN);

  // ---- init (1 dispatch replaces 5 memsets) + weight casts (1 dispatch) ----
  init_kernel<<<(NNODES + 255) / 256, 256, 0, stream>>>(deg, eS1, eD1, eS2, eD2);
  cast_weights<<<(W1N4 + W2N4 + 255) / 256, 256, 0, stream>>>(W1, W2, Wb1, Wb2);

  // ---- CSR build (edge list identical for both layers) ----
  degree_kernel<<<(ETOT + 255) / 256, 256, 0, stream>>>(ei, deg);
  scan_blocksums<<<NSCAN, 256, 0, stream>>>(deg, bsums);
  scan_bsums<<<1, 64, 0, stream>>>(bsums, boffs, rowptr);
  scan_final<<<NSCAN, 256, 0, stream>>>(deg, boffs, rowptr, cursor);
  scatter_kernel<<<(ETOT + 255) / 256, 256, 0, stream>>>(ei, cursor, csrsrc);

  dim3 gemm_grid(2, (NNODES + TM - 1) / TM);
  int nblk4 = (NNODES + 3) / 4;

  // ---- layer 1 (x fp32 converted in GEMM staging; score fused in epilogue) ----
  gemm_bf16<<<gemm_grid, 256, 0, stream>>>(x, (const unsigned short*)nullptr, DIN,
                                           Wb1, DIN, Hmb, NNODES, a1s, a1d, eS1, eD1);
  aggregate_kernel<<<nblk4, 256, 0, stream>>>(Hmb, eS1, eD1, rowptr, csrsrc, b1, out, 0, Xb);

  // ---- layer 2 ----
  gemm_bf16<<<gemm_grid, 256, 0, stream>>>((const float*)nullptr, Xb, CH,
                                           Wb2, CH, Hmb, NNODES, a2s, a2d, eS2, eD2);
  aggregate_kernel<<<nblk4, 256, 0, stream>>>(Hmb, eS2, eD2, rowptr, csrsrc, b2, out, 256, (unsigned short*)nullptr);
}